// Round 9
// baseline (1303.481 us; speedup 1.0000x reference)
//
#include <hip/hip_runtime.h>

#define NCLS 1000
#define DIM 256
#define GCAP 500
#define NT32 32                    // 32 tiles of 32 cols over 1024 padded cols
#define SCLF 20.609930f            // 1/(0.07*ln2)
#define CP 23.0f
#define CPLN2 15.94238515f         // 23*ln2
#define LN2 0.69314718056f
#define PADC 2.86102294921875e-06f // 24 * 2^-23 (pad-column contribution)

typedef __attribute__((ext_vector_type(8))) short short8;
typedef __attribute__((ext_vector_type(4))) float f32x4;

__device__ __forceinline__ short f2bf(float f) {
  unsigned u = __float_as_uint(f);
  unsigned r = u + 0x7fffu + ((u >> 16) & 1u);
  return (short)(r >> 16);
}
__device__ __forceinline__ float fexp2(float x) {
#if __has_builtin(__builtin_amdgcn_exp2f)
  return __builtin_amdgcn_exp2f(x);
#else
  return exp2f(x);
#endif
}
__device__ __forceinline__ void gload_lds16(const void* g, void* l) {
  __builtin_amdgcn_global_load_lds(
      (const __attribute__((address_space(1))) unsigned int*)g,
      (__attribute__((address_space(3))) unsigned int*)l, 16, 0, 0);
}

// ---------------- K0: scatter rows into per-class lists ------------------------
__global__ __launch_bounds__(256) void scatter_kernel(
    const int* __restrict__ sl, const int* __restrict__ tl, int N,
    int* __restrict__ gcnt, int* __restrict__ glist) {
  const int i = blockIdx.x * 256 + threadIdx.x;
  if (i >= 2 * N) return;
  const int side = (i >= N) ? 1 : 0;
  const int r = i - side * N;
  const int c = (side ? tl : sl)[r];
  const int bin = side * NCLS + c;
  const int slot = atomicAdd(gcnt + bin, 1);
  if (slot < GCAP) glist[(size_t)bin * GCAP + slot] = r;
}

// ---------------- K1: per-class gather + mean + normalize ----------------------
__global__ __launch_bounds__(256) void proto_kernel(
    const float* __restrict__ sf, const float* __restrict__ tf,
    const int* __restrict__ gcnt, const int* __restrict__ glist,
    float* __restrict__ mean_out, float* __restrict__ spn, float* __restrict__ tpn,
    unsigned short* __restrict__ pbf) {
  const int bid = blockIdx.x;
  const int side = (bid >= NCLS) ? 1 : 0;
  const int c = bid - side * NCLS;
  const float* feats = side ? tf : sf;
  const int* list = glist + (size_t)bid * GCAP;
  const int m = min(gcnt[bid], GCAP);
  const int t = threadIdx.x;
  __shared__ float s_red[4];

  float a0 = 0.f, a1 = 0.f, a2 = 0.f, a3 = 0.f, a4 = 0.f, a5 = 0.f, a6 = 0.f, a7 = 0.f;
  int i = 0;
  for (; i + 8 <= m; i += 8) {
    a0 += feats[(size_t)list[i + 0] * DIM + t];
    a1 += feats[(size_t)list[i + 1] * DIM + t];
    a2 += feats[(size_t)list[i + 2] * DIM + t];
    a3 += feats[(size_t)list[i + 3] * DIM + t];
    a4 += feats[(size_t)list[i + 4] * DIM + t];
    a5 += feats[(size_t)list[i + 5] * DIM + t];
    a6 += feats[(size_t)list[i + 6] * DIM + t];
    a7 += feats[(size_t)list[i + 7] * DIM + t];
  }
  for (; i < m; i++) a0 += feats[(size_t)list[i] * DIM + t];
  const float sum = ((a0 + a1) + (a2 + a3)) + ((a4 + a5) + (a6 + a7));
  const float mean = sum / fmaxf((float)m, 1.0f);
  if (!side) mean_out[(size_t)c * DIM + t] = mean;

  float ss = mean * mean;
  #pragma unroll
  for (int o = 1; o < 64; o <<= 1) ss += __shfl_xor(ss, o);
  if ((t & 63) == 0) s_red[t >> 6] = ss;
  __syncthreads();
  const float tot = s_red[0] + s_red[1] + s_red[2] + s_red[3];
  const float innv = 1.0f / fmaxf(sqrtf(tot), 1e-12f);
  const float p = mean * innv;
  (side ? tpn : spn)[(size_t)c * DIM + t] = p;
  if (!side) {
    // tiled bf16 layout: [c>>4][kf=t>>5][lg=(t>>3)&3][c&15][e=t&7]
    size_t off = (size_t)(c >> 4) * 4096 + (size_t)(t >> 5) * 512
               + (size_t)((t >> 3) & 3) * 128 + (size_t)(c & 15) * 8 + (t & 7);
    pbf[off] = (unsigned short)f2bf(p);
  }
}

// ---------------- K2: structure matrices + struct loss (fp32, 64x64 tiles) -----
__global__ __launch_bounds__(256) void struct_kernel(
    const float* __restrict__ spn, const float* __restrict__ tpn,
    float* __restrict__ out_struct, float* __restrict__ acc) {
  __shared__ float Sa[16][68], Sb[16][68], Ta[16][68], Tb[16][68];
  __shared__ float red[256];
  const int t = threadIdx.x;
  const int tx = t & 15, ty = t >> 4;
  const int i0 = blockIdx.y * 64, j0 = blockIdx.x * 64;
  float cs[4][4], cg[4][4];
  #pragma unroll
  for (int a = 0; a < 4; a++)
    #pragma unroll
    for (int b = 0; b < 4; b++) { cs[a][b] = 0.f; cg[a][b] = 0.f; }

  const int srow = t >> 2;
  const int skq = (t & 3) * 4;
  for (int k0 = 0; k0 < DIM; k0 += 16) {
    __syncthreads();
    {
      float4 z = make_float4(0.f, 0.f, 0.f, 0.f);
      int ra = i0 + srow, rb = j0 + srow;
      float4 va = (ra < NCLS) ? *(const float4*)(spn + (size_t)ra * DIM + k0 + skq) : z;
      float4 vb = (rb < NCLS) ? *(const float4*)(spn + (size_t)rb * DIM + k0 + skq) : z;
      float4 wa = (ra < NCLS) ? *(const float4*)(tpn + (size_t)ra * DIM + k0 + skq) : z;
      float4 wb = (rb < NCLS) ? *(const float4*)(tpn + (size_t)rb * DIM + k0 + skq) : z;
      Sa[skq+0][srow]=va.x; Sa[skq+1][srow]=va.y; Sa[skq+2][srow]=va.z; Sa[skq+3][srow]=va.w;
      Sb[skq+0][srow]=vb.x; Sb[skq+1][srow]=vb.y; Sb[skq+2][srow]=vb.z; Sb[skq+3][srow]=vb.w;
      Ta[skq+0][srow]=wa.x; Ta[skq+1][srow]=wa.y; Ta[skq+2][srow]=wa.z; Ta[skq+3][srow]=wa.w;
      Tb[skq+0][srow]=wb.x; Tb[skq+1][srow]=wb.y; Tb[skq+2][srow]=wb.z; Tb[skq+3][srow]=wb.w;
    }
    __syncthreads();
    #pragma unroll
    for (int k = 0; k < 16; k++) {
      float a[4], b[4], c[4], d[4];
      *(float4*)a = *(const float4*)&Sa[k][ty * 4];
      *(float4*)b = *(const float4*)&Sb[k][tx * 4];
      *(float4*)c = *(const float4*)&Ta[k][ty * 4];
      *(float4*)d = *(const float4*)&Tb[k][tx * 4];
      #pragma unroll
      for (int ii = 0; ii < 4; ii++)
        #pragma unroll
        for (int jj = 0; jj < 4; jj++) {
          cs[ii][jj] = fmaf(a[ii], b[jj], cs[ii][jj]);
          cg[ii][jj] = fmaf(c[ii], d[jj], cg[ii][jj]);
        }
    }
  }
  float d2 = 0.f;
  #pragma unroll
  for (int ii = 0; ii < 4; ii++) {
    int gi = i0 + ty * 4 + ii;
    if (gi < NCLS) {
      #pragma unroll
      for (int jj = 0; jj < 4; jj++) {
        int gj = j0 + tx * 4 + jj;
        if (gj < NCLS) {
          out_struct[(size_t)gi * NCLS + gj] = cs[ii][jj];
          float df = cs[ii][jj] - cg[ii][jj];
          d2 += df * df;
        }
      }
    }
  }
  red[t] = d2;
  __syncthreads();
  for (int o = 128; o > 0; o >>= 1) { if (t < o) red[t] += red[t + o]; __syncthreads(); }
  if (t == 0) atomicAdd(acc, red[0]);
}

// ------- K3: contrastive loss — rf=4 (64 rows/wave), plain 2-phase dbuf --------
// R3's register shape (proven no-spill) x R4's schedule (proven 227us) x occ 3.
__global__ __launch_bounds__(256, 3) void contrast_kernel(
    const float* __restrict__ feats, const int* __restrict__ labels,
    const unsigned short* __restrict__ pbf,
    float* __restrict__ acc_out, int N) {
  __shared__ __align__(16) unsigned short Bt[2][8192];  // 2 x 16KB (32-col tiles)
  __shared__ float red[256];
  const int t = threadIdx.x;
  const int lane = t & 63, w = t >> 6;
  const int lx = lane & 15, lg = lane >> 4;
  const int row0 = blockIdx.x * 1024 + w * 256;  // 256 rows per wave? no: see below
  // NOTE: 4 waves x 64 rows = 256 rows per block
  const int rbase = blockIdx.x * 256 + w * 64;
  const float4 z4 = make_float4(0.f, 0.f, 0.f, 0.f);

  short8 af[4][8];       // 64 rows/wave, unscaled bf16
  float sclF[4][4];      // (1/(T*ln2))/||f|| per owned row
  float sSt[4][4], labD[4][4];
  int cp[4];             // packed label tile-codes (4 x 8-bit per rf)

  #pragma unroll
  for (int rf = 0; rf < 4; rf++) {
    const int r = rbase + rf * 16 + lx;
    const bool v = r < N;
    const float* rp = feats + (size_t)r * DIM + (lg << 3);
    float n2 = 0.f;
    #pragma unroll
    for (int kf = 0; kf < 8; kf++) {
      float4 x = v ? *(const float4*)(rp + kf * 32)     : z4;
      float4 y = v ? *(const float4*)(rp + kf * 32 + 4) : z4;
      n2 += x.x*x.x + x.y*x.y + x.z*x.z + x.w*x.w
          + y.x*y.x + y.y*y.y + y.z*y.z + y.w*y.w;
      short8 f;
      f[0] = f2bf(x.x); f[1] = f2bf(x.y); f[2] = f2bf(x.z); f[3] = f2bf(x.w);
      f[4] = f2bf(y.x); f[5] = f2bf(y.y); f[6] = f2bf(y.z); f[7] = f2bf(y.w);
      af[rf][kf] = f;
    }
    n2 += __shfl_xor(n2, 16);
    n2 += __shfl_xor(n2, 32);
    const float sw = SCLF / fmaxf(sqrtf(n2), 1e-12f);
    int pc = 0;
    #pragma unroll
    for (int reg = 0; reg < 4; reg++) {
      sclF[rf][reg] = __shfl(sw, (lg << 2) | reg);
      const int row = rbase + rf * 16 + (lg << 2) + reg;
      const int lb = (row < N) ? labels[row] : -1;
      const int tidx = (lb >= 0 && (lb & 15) == lx) ? (lb >> 4) : 255;
      pc |= tidx << (reg * 8);
      sSt[rf][reg] = 0.f;
      labD[rf][reg] = 0.f;
    }
    cp[rf] = pc;
  }

  // stage a 32-col tile (16KB = 8192 ushorts): per wave 4 x 1KB linear copies
  #define STAGE(cf_, buf_)                                                          \
    {                                                                               \
      const unsigned short* g0 = pbf + ((size_t)(cf_) << 13) + (w << 9) + (lane << 3); \
      _Pragma("unroll")                                                             \
      for (int q = 0; q < 4; q++)                                                   \
        gload_lds16(g0 + (q << 11), &Bt[buf_][(q << 11) + (w << 9)]);               \
    }

  int cur = 0;
  STAGE(0, 0);
  __syncthreads();

  for (int cf = 0; cf < NT32; cf++) {
    if (cf < NT32 - 1) STAGE(cf + 1, cur ^ 1);

    const unsigned short* bb = &Bt[cur][(lg << 7) + (lx << 3)];
    #pragma unroll
    for (int s = 0; s < 2; s++) {
      const unsigned short* bs = bb + (s << 12);
      f32x4 d0 = {0.f, 0.f, 0.f, 0.f};
      f32x4 d1 = {0.f, 0.f, 0.f, 0.f};
      f32x4 d2 = {0.f, 0.f, 0.f, 0.f};
      f32x4 d3 = {0.f, 0.f, 0.f, 0.f};
      #pragma unroll
      for (int kf = 0; kf < 8; kf++) {
        short8 b = *(const short8*)(bs + (kf << 9));
        d0 = __builtin_amdgcn_mfma_f32_16x16x32_bf16(af[0][kf], b, d0, 0, 0, 0);
        d1 = __builtin_amdgcn_mfma_f32_16x16x32_bf16(af[1][kf], b, d1, 0, 0, 0);
        d2 = __builtin_amdgcn_mfma_f32_16x16x32_bf16(af[2][kf], b, d2, 0, 0, 0);
        d3 = __builtin_amdgcn_mfma_f32_16x16x32_bf16(af[3][kf], b, d3, 0, 0, 0);
      }
      const int g = 2 * cf + s;
      #pragma unroll
      for (int reg = 0; reg < 4; reg++) {
        sSt[0][reg] += fexp2(fmaf(d0[reg], sclF[0][reg], -CP));
        sSt[1][reg] += fexp2(fmaf(d1[reg], sclF[1][reg], -CP));
        sSt[2][reg] += fexp2(fmaf(d2[reg], sclF[2][reg], -CP));
        sSt[3][reg] += fexp2(fmaf(d3[reg], sclF[3][reg], -CP));
        labD[0][reg] += (((cp[0] >> (reg * 8)) & 255) == g) ? d0[reg] : 0.f;
        labD[1][reg] += (((cp[1] >> (reg * 8)) & 255) == g) ? d1[reg] : 0.f;
        labD[2][reg] += (((cp[2] >> (reg * 8)) & 255) == g) ? d2[reg] : 0.f;
        labD[3][reg] += (((cp[3] >> (reg * 8)) & 255) == g) ? d3[reg] : 0.f;
      }
    }
    __syncthreads();
    cur ^= 1;
  }

  float wl = 0.f;
  #pragma unroll
  for (int rf = 0; rf < 4; rf++)
    #pragma unroll
    for (int reg = 0; reg < 4; reg++) {
      float s = sSt[rf][reg], lb = labD[rf][reg];
      #pragma unroll
      for (int o = 1; o < 16; o <<= 1) { s += __shfl_xor(s, o); lb += __shfl_xor(lb, o); }
      const int row = rbase + rf * 16 + (lg << 2) + reg;
      if (lx == 0 && row < N)
        wl += logf(s - PADC) + CPLN2 - lb * sclF[rf][reg] * LN2;
    }

  red[t] = wl;
  __syncthreads();
  for (int o = 128; o > 0; o >>= 1) { if (t < o) red[t] += red[t + o]; __syncthreads(); }
  if (t == 0) atomicAdd(acc_out, red[0]);
}

// ---------------- K4: scalars ---------------------------------------------------
__global__ void final_kernel(const float* __restrict__ acc, float* __restrict__ out, int N) {
  out[0] = acc[0] * (1.0f / (float)(NCLS * NCLS));
  out[1] = acc[1] / (float)N;
}

extern "C" void kernel_launch(void* const* d_in, const int* in_sizes, int n_in,
                              void* d_out, int out_size, void* d_ws, size_t ws_size,
                              hipStream_t stream) {
  const float* src_feats  = (const float*)d_in[0];
  const int*   src_labels = (const int*)d_in[1];
  const float* tgt_feats  = (const float*)d_in[2];
  const int*   tgt_labels = (const int*)d_in[3];
  const int N = in_sizes[0] / DIM;

  // ws layout (floats):
  // [0,16)           acc: [0]=struct sq-sum, [1]=contrast sum
  // [16,256016)      src_pn
  // [256016,512016)  tgt_pn
  // [512016,643088)  pbf: 64 tiles x 4096 ushorts (1024 padded cols)
  // [643088,645088)  gcnt: 2000 ints
  float* ws = (float*)d_ws;
  float* acc    = ws;
  float* src_pn = ws + 16;
  float* tgt_pn = ws + 256016;
  unsigned short* pbf = (unsigned short*)(ws + 512016);
  int* gcnt = (int*)(ws + 643088);

  float* out_f      = (float*)d_out;
  float* out_protos = out_f + 2;
  float* out_struct = out_f + 2 + NCLS * DIM;
  // glist borrows the out_struct region (1M ints); struct_kernel overwrites it later
  int* glist = (int*)out_struct;

  hipMemsetAsync(acc, 0, 2 * sizeof(float), stream);
  hipMemsetAsync(gcnt, 0, 2 * NCLS * sizeof(int), stream);
  hipMemsetAsync(pbf + 62 * 4096, 0, 2 * 4096 * sizeof(unsigned short), stream);

  int sblocks = (2 * N + 255) / 256;
  scatter_kernel<<<sblocks, 256, 0, stream>>>(src_labels, tgt_labels, N, gcnt, glist);

  proto_kernel<<<2 * NCLS, 256, 0, stream>>>(src_feats, tgt_feats, gcnt, glist,
                                             out_protos, src_pn, tgt_pn, pbf);

  dim3 sgrid(16, 16);
  struct_kernel<<<sgrid, 256, 0, stream>>>(src_pn, tgt_pn, out_struct, acc);

  int cblocks = (N + 255) / 256;
  contrast_kernel<<<cblocks, 256, 0, stream>>>(src_feats, src_labels, pbf, acc + 1, N);

  final_kernel<<<1, 1, 0, stream>>>(acc, out_f, N);
}

// Round 10
// 417.139 us; speedup vs baseline: 3.1248x; 3.1248x over previous
//
#include <hip/hip_runtime.h>

#define NCLS 1000
#define DIM 256
#define GCAP 500
#define NT16 64                    // 64 tiles of 16 cols over 1024 padded cols
#define SCLF 20.609930f            // 1/(0.07*ln2)
#define CP 23.0f
#define CPLN2 15.94238515f         // 23*ln2
#define LN2 0.69314718056f
#define PADC 2.86102294921875e-06f // 24 * 2^-23 (pad-column contribution)

typedef __attribute__((ext_vector_type(8))) short short8;
typedef __attribute__((ext_vector_type(4))) float f32x4;

__device__ __forceinline__ short f2bf(float f) {
  unsigned u = __float_as_uint(f);
  unsigned r = u + 0x7fffu + ((u >> 16) & 1u);
  return (short)(r >> 16);
}
__device__ __forceinline__ float fexp2(float x) {
#if __has_builtin(__builtin_amdgcn_exp2f)
  return __builtin_amdgcn_exp2f(x);
#else
  return exp2f(x);
#endif
}
__device__ __forceinline__ void gload_lds16(const void* g, void* l) {
  __builtin_amdgcn_global_load_lds(
      (const __attribute__((address_space(1))) unsigned int*)g,
      (__attribute__((address_space(3))) unsigned int*)l, 16, 0, 0);
}

// ---------------- K0: scatter rows into per-class lists ------------------------
__global__ __launch_bounds__(256) void scatter_kernel(
    const int* __restrict__ sl, const int* __restrict__ tl, int N,
    int* __restrict__ gcnt, int* __restrict__ glist) {
  const int i = blockIdx.x * 256 + threadIdx.x;
  if (i >= 2 * N) return;
  const int side = (i >= N) ? 1 : 0;
  const int r = i - side * N;
  const int c = (side ? tl : sl)[r];
  const int bin = side * NCLS + c;
  const int slot = atomicAdd(gcnt + bin, 1);
  if (slot < GCAP) glist[(size_t)bin * GCAP + slot] = r;
}

// ---------------- K1: per-class gather + mean + normalize ----------------------
__global__ __launch_bounds__(256) void proto_kernel(
    const float* __restrict__ sf, const float* __restrict__ tf,
    const int* __restrict__ gcnt, const int* __restrict__ glist,
    float* __restrict__ mean_out, float* __restrict__ spn, float* __restrict__ tpn,
    unsigned short* __restrict__ pbf) {
  const int bid = blockIdx.x;
  const int side = (bid >= NCLS) ? 1 : 0;
  const int c = bid - side * NCLS;
  const float* feats = side ? tf : sf;
  const int* list = glist + (size_t)bid * GCAP;
  const int m = min(gcnt[bid], GCAP);
  const int t = threadIdx.x;
  __shared__ float s_red[4];

  float a0 = 0.f, a1 = 0.f, a2 = 0.f, a3 = 0.f, a4 = 0.f, a5 = 0.f, a6 = 0.f, a7 = 0.f;
  int i = 0;
  for (; i + 8 <= m; i += 8) {
    a0 += feats[(size_t)list[i + 0] * DIM + t];
    a1 += feats[(size_t)list[i + 1] * DIM + t];
    a2 += feats[(size_t)list[i + 2] * DIM + t];
    a3 += feats[(size_t)list[i + 3] * DIM + t];
    a4 += feats[(size_t)list[i + 4] * DIM + t];
    a5 += feats[(size_t)list[i + 5] * DIM + t];
    a6 += feats[(size_t)list[i + 6] * DIM + t];
    a7 += feats[(size_t)list[i + 7] * DIM + t];
  }
  for (; i < m; i++) a0 += feats[(size_t)list[i] * DIM + t];
  const float sum = ((a0 + a1) + (a2 + a3)) + ((a4 + a5) + (a6 + a7));
  const float mean = sum / fmaxf((float)m, 1.0f);
  if (!side) mean_out[(size_t)c * DIM + t] = mean;

  float ss = mean * mean;
  #pragma unroll
  for (int o = 1; o < 64; o <<= 1) ss += __shfl_xor(ss, o);
  if ((t & 63) == 0) s_red[t >> 6] = ss;
  __syncthreads();
  const float tot = s_red[0] + s_red[1] + s_red[2] + s_red[3];
  const float innv = 1.0f / fmaxf(sqrtf(tot), 1e-12f);
  const float p = mean * innv;
  (side ? tpn : spn)[(size_t)c * DIM + t] = p;
  if (!side) {
    // tiled bf16 layout: [c>>4][kf=t>>5][lg=(t>>3)&3][c&15][e=t&7]
    size_t off = (size_t)(c >> 4) * 4096 + (size_t)(t >> 5) * 512
               + (size_t)((t >> 3) & 3) * 128 + (size_t)(c & 15) * 8 + (t & 7);
    pbf[off] = (unsigned short)f2bf(p);
  }
}

// ---------------- K2: structure matrices + struct loss (fp32, 64x64 tiles) -----
__global__ __launch_bounds__(256) void struct_kernel(
    const float* __restrict__ spn, const float* __restrict__ tpn,
    float* __restrict__ out_struct, float* __restrict__ acc) {
  __shared__ float Sa[16][68], Sb[16][68], Ta[16][68], Tb[16][68];
  __shared__ float red[256];
  const int t = threadIdx.x;
  const int tx = t & 15, ty = t >> 4;
  const int i0 = blockIdx.y * 64, j0 = blockIdx.x * 64;
  float cs[4][4], cg[4][4];
  #pragma unroll
  for (int a = 0; a < 4; a++)
    #pragma unroll
    for (int b = 0; b < 4; b++) { cs[a][b] = 0.f; cg[a][b] = 0.f; }

  const int srow = t >> 2;
  const int skq = (t & 3) * 4;
  for (int k0 = 0; k0 < DIM; k0 += 16) {
    __syncthreads();
    {
      float4 z = make_float4(0.f, 0.f, 0.f, 0.f);
      int ra = i0 + srow, rb = j0 + srow;
      float4 va = (ra < NCLS) ? *(const float4*)(spn + (size_t)ra * DIM + k0 + skq) : z;
      float4 vb = (rb < NCLS) ? *(const float4*)(spn + (size_t)rb * DIM + k0 + skq) : z;
      float4 wa = (ra < NCLS) ? *(const float4*)(tpn + (size_t)ra * DIM + k0 + skq) : z;
      float4 wb = (rb < NCLS) ? *(const float4*)(tpn + (size_t)rb * DIM + k0 + skq) : z;
      Sa[skq+0][srow]=va.x; Sa[skq+1][srow]=va.y; Sa[skq+2][srow]=va.z; Sa[skq+3][srow]=va.w;
      Sb[skq+0][srow]=vb.x; Sb[skq+1][srow]=vb.y; Sb[skq+2][srow]=vb.z; Sb[skq+3][srow]=vb.w;
      Ta[skq+0][srow]=wa.x; Ta[skq+1][srow]=wa.y; Ta[skq+2][srow]=wa.z; Ta[skq+3][srow]=wa.w;
      Tb[skq+0][srow]=wb.x; Tb[skq+1][srow]=wb.y; Tb[skq+2][srow]=wb.z; Tb[skq+3][srow]=wb.w;
    }
    __syncthreads();
    #pragma unroll
    for (int k = 0; k < 16; k++) {
      float a[4], b[4], c[4], d[4];
      *(float4*)a = *(const float4*)&Sa[k][ty * 4];
      *(float4*)b = *(const float4*)&Sb[k][tx * 4];
      *(float4*)c = *(const float4*)&Ta[k][ty * 4];
      *(float4*)d = *(const float4*)&Tb[k][tx * 4];
      #pragma unroll
      for (int ii = 0; ii < 4; ii++)
        #pragma unroll
        for (int jj = 0; jj < 4; jj++) {
          cs[ii][jj] = fmaf(a[ii], b[jj], cs[ii][jj]);
          cg[ii][jj] = fmaf(c[ii], d[jj], cg[ii][jj]);
        }
    }
  }
  float d2 = 0.f;
  #pragma unroll
  for (int ii = 0; ii < 4; ii++) {
    int gi = i0 + ty * 4 + ii;
    if (gi < NCLS) {
      #pragma unroll
      for (int jj = 0; jj < 4; jj++) {
        int gj = j0 + tx * 4 + jj;
        if (gj < NCLS) {
          out_struct[(size_t)gi * NCLS + gj] = cs[ii][jj];
          float df = cs[ii][jj] - cg[ii][jj];
          d2 += df * df;
        }
      }
    }
  }
  red[t] = d2;
  __syncthreads();
  for (int o = 128; o > 0; o >>= 1) { if (t < o) red[t] += red[t + o]; __syncthreads(); }
  if (t == 0) atomicAdd(acc, red[0]);
}

// ------- K3: contrastive loss — rf=2, 16-col tiles, 16.4KB LDS, high TLP -------
// R4's exact register/schedule shape (VGPR=64 proven), tile halved so ~7 blocks/CU.
__global__ __launch_bounds__(256, 4) void contrast_kernel(
    const float* __restrict__ feats, const int* __restrict__ labels,
    const unsigned short* __restrict__ pbf,
    float* __restrict__ acc_out, int N) {
  __shared__ __align__(16) unsigned short Bt[2][4096];  // 2 x 8KB (16-col tiles)
  float* red = (float*)&Bt[0][0];                       // aliased: used after loop
  const int t = threadIdx.x;
  const int lane = t & 63, w = t >> 6;
  const int lx = lane & 15, lg = lane >> 4;
  const int row0 = blockIdx.x * 128 + w * 32;
  const float4 z4 = make_float4(0.f, 0.f, 0.f, 0.f);

  short8 af[2][8];           // 32 rows/wave, unscaled bf16
  float sclF[2][4];          // (1/(T*ln2))/||f|| per owned row
  float sSt[2][4], labD[2][4];
  int code[2][4];            // label's 16-col tile index if lx matches, else big

  #pragma unroll
  for (int rf = 0; rf < 2; rf++) {
    const int r = row0 + rf * 16 + lx;
    const bool v = r < N;
    const float* rp = feats + (size_t)r * DIM + (lg << 3);
    float n2 = 0.f;
    #pragma unroll
    for (int kf = 0; kf < 8; kf++) {
      float4 x = v ? *(const float4*)(rp + kf * 32)     : z4;
      float4 y = v ? *(const float4*)(rp + kf * 32 + 4) : z4;
      n2 += x.x*x.x + x.y*x.y + x.z*x.z + x.w*x.w
          + y.x*y.x + y.y*y.y + y.z*y.z + y.w*y.w;
      short8 f;
      f[0] = f2bf(x.x); f[1] = f2bf(x.y); f[2] = f2bf(x.z); f[3] = f2bf(x.w);
      f[4] = f2bf(y.x); f[5] = f2bf(y.y); f[6] = f2bf(y.z); f[7] = f2bf(y.w);
      af[rf][kf] = f;
    }
    n2 += __shfl_xor(n2, 16);
    n2 += __shfl_xor(n2, 32);
    const float sw = SCLF / fmaxf(sqrtf(n2), 1e-12f);
    #pragma unroll
    for (int reg = 0; reg < 4; reg++) {
      sclF[rf][reg] = __shfl(sw, (lg << 2) | reg);
      const int row = row0 + rf * 16 + (lg << 2) + reg;
      const int lb = (row < N) ? labels[row] : -1;
      code[rf][reg] = (lb >= 0 && (lb & 15) == lx) ? (lb >> 4) : 0x7fff;
      sSt[rf][reg] = 0.f;
      labD[rf][reg] = 0.f;
    }
  }

  // stage a 16-col tile (8KB = 4096 ushorts): per wave 2 x 1KB linear copies
  #define STAGE(cf_, buf_)                                                           \
    {                                                                                \
      const unsigned short* g0 = pbf + ((size_t)(cf_) << 12) + (w << 9) + (lane << 3); \
      gload_lds16(g0,        &Bt[buf_][(w << 9)]);                                   \
      gload_lds16(g0 + 2048, &Bt[buf_][2048 + (w << 9)]);                            \
    }

  int cur = 0;
  STAGE(0, 0);
  __syncthreads();

  for (int cf = 0; cf < NT16; cf++) {
    if (cf < NT16 - 1) STAGE(cf + 1, cur ^ 1);

    const unsigned short* bb = &Bt[cur][(lg << 7) + (lx << 3)];
    f32x4 d0 = {0.f, 0.f, 0.f, 0.f};
    f32x4 d1 = {0.f, 0.f, 0.f, 0.f};
    #pragma unroll
    for (int kf = 0; kf < 8; kf++) {
      short8 b = *(const short8*)(bb + (kf << 9));
      d0 = __builtin_amdgcn_mfma_f32_16x16x32_bf16(af[0][kf], b, d0, 0, 0, 0);
      d1 = __builtin_amdgcn_mfma_f32_16x16x32_bf16(af[1][kf], b, d1, 0, 0, 0);
    }
    #pragma unroll
    for (int reg = 0; reg < 4; reg++) {
      sSt[0][reg] += fexp2(fmaf(d0[reg], sclF[0][reg], -CP));
      sSt[1][reg] += fexp2(fmaf(d1[reg], sclF[1][reg], -CP));
      labD[0][reg] += (code[0][reg] == cf) ? d0[reg] : 0.f;
      labD[1][reg] += (code[1][reg] == cf) ? d1[reg] : 0.f;
    }
    __syncthreads();
    cur ^= 1;
  }

  float wl = 0.f;
  #pragma unroll
  for (int rf = 0; rf < 2; rf++)
    #pragma unroll
    for (int reg = 0; reg < 4; reg++) {
      float s = sSt[rf][reg], lb = labD[rf][reg];
      #pragma unroll
      for (int o = 1; o < 16; o <<= 1) { s += __shfl_xor(s, o); lb += __shfl_xor(lb, o); }
      const int row = row0 + rf * 16 + (lg << 2) + reg;
      if (lx == 0 && row < N)
        wl += logf(s - PADC) + CPLN2 - lb * sclF[rf][reg] * LN2;
    }

  __syncthreads();            // Bt dead; red aliases it
  red[t] = wl;
  __syncthreads();
  for (int o = 128; o > 0; o >>= 1) { if (t < o) red[t] += red[t + o]; __syncthreads(); }
  if (t == 0) atomicAdd(acc_out, red[0]);
}

// ---------------- K4: scalars ---------------------------------------------------
__global__ void final_kernel(const float* __restrict__ acc, float* __restrict__ out, int N) {
  out[0] = acc[0] * (1.0f / (float)(NCLS * NCLS));
  out[1] = acc[1] / (float)N;
}

extern "C" void kernel_launch(void* const* d_in, const int* in_sizes, int n_in,
                              void* d_out, int out_size, void* d_ws, size_t ws_size,
                              hipStream_t stream) {
  const float* src_feats  = (const float*)d_in[0];
  const int*   src_labels = (const int*)d_in[1];
  const float* tgt_feats  = (const float*)d_in[2];
  const int*   tgt_labels = (const int*)d_in[3];
  const int N = in_sizes[0] / DIM;

  // ws layout (floats):
  // [0,16)           acc: [0]=struct sq-sum, [1]=contrast sum
  // [16,256016)      src_pn
  // [256016,512016)  tgt_pn
  // [512016,643088)  pbf: 64 tiles x 4096 ushorts (1024 padded cols)
  // [643088,645088)  gcnt: 2000 ints
  float* ws = (float*)d_ws;
  float* acc    = ws;
  float* src_pn = ws + 16;
  float* tgt_pn = ws + 256016;
  unsigned short* pbf = (unsigned short*)(ws + 512016);
  int* gcnt = (int*)(ws + 643088);

  float* out_f      = (float*)d_out;
  float* out_protos = out_f + 2;
  float* out_struct = out_f + 2 + NCLS * DIM;
  // glist borrows the out_struct region (1M ints); struct_kernel overwrites it later
  int* glist = (int*)out_struct;

  hipMemsetAsync(acc, 0, 2 * sizeof(float), stream);
  hipMemsetAsync(gcnt, 0, 2 * NCLS * sizeof(int), stream);
  hipMemsetAsync(pbf + 62 * 4096, 0, 2 * 4096 * sizeof(unsigned short), stream);

  int sblocks = (2 * N + 255) / 256;
  scatter_kernel<<<sblocks, 256, 0, stream>>>(src_labels, tgt_labels, N, gcnt, glist);

  proto_kernel<<<2 * NCLS, 256, 0, stream>>>(src_feats, tgt_feats, gcnt, glist,
                                             out_protos, src_pn, tgt_pn, pbf);

  dim3 sgrid(16, 16);
  struct_kernel<<<sgrid, 256, 0, stream>>>(src_pn, tgt_pn, out_struct, acc);

  int cblocks = (N + 127) / 128;
  contrast_kernel<<<cblocks, 256, 0, stream>>>(src_feats, src_labels, pbf, acc + 1, N);

  final_kernel<<<1, 1, 0, stream>>>(acc, out_f, N);
}